// Round 1
// baseline (321.095 us; speedup 1.0000x reference)
//
#include <hip/hip_runtime.h>

typedef short v8s __attribute__((ext_vector_type(8)));
typedef float v4f __attribute__((ext_vector_type(4)));

#define BATCH 16
#define NBATCH 128           // 2048 / 16
#define BH 16384             // B*H
#define TBH 33554432         // T*B*H

__device__ __forceinline__ ushort f2bf(float f) {
  // round-to-nearest-even fp32 -> bf16 (inputs finite, no NaN handling needed)
  uint u = __float_as_uint(f);
  u += 0x7FFF + ((u >> 16) & 1);
  return (ushort)(u >> 16);
}

// pack 2 fp32 -> 2 bf16 in one uint via the HW pack-convert (1 VALU op vs ~9)
__device__ __forceinline__ uint pkbf2(float a, float b) {
  uint r;
  asm("v_cvt_pk_bf16_f32 %0, %1, %2" : "=v"(r) : "v"(a), "v"(b));
  return r;
}

union frag_u { uint u[4]; v8s s; };

// ---------------- Phase 1: xW[m,h] = sum_i x[m,i] * W[h,i] ----------------
// LDS-free, barrier-free streaming GEMM:
//   - each wave owns a 64-col slice of H; W slice lives in 128 VGPRs (bf16 frags)
//   - A streamed in 16-row chunks, global->VGPR->cvt_pk->MFMA, half-buffered
//   - 512 blocks x 4 waves; block covers 256 rows (16 chunks); 4 waves share A via L1
__global__ __launch_bounds__(256, 2) void indrnn_gemm(
    const float* __restrict__ A,
    const float* __restrict__ W,
    ushort* __restrict__ C)
{
  const int tid  = threadIdx.x;
  const int lane = tid & 63;
  const int wv   = tid >> 6;       // 0..3 -> which 64-col slice of H
  const int l15  = lane & 15;
  const int lhi  = lane >> 4;      // 0..3
  const int c0   = wv * 64;
  const int rowblk = blockIdx.x * 256;

  // ---- W fragments resident in VGPRs: wfr[nt][kk] = cols c0+nt*16..+15, k kk*32..+31 ----
  // B-frag layout (m89-verified): lane supplies col=l15, k=(lane>>4)*8 + j, j=0..7
  frag_u wfr[4][8];
  #pragma unroll
  for (int nt = 0; nt < 4; ++nt) {
    const float* pw = W + (((size_t)(c0 + nt * 16 + l15)) << 8) + (lhi << 3);
    #pragma unroll
    for (int kk = 0; kk < 8; ++kk) {
      const float4 w0 = *(const float4*)(pw + kk * 32);
      const float4 w1 = *(const float4*)(pw + kk * 32 + 4);
      wfr[nt][kk].u[0] = pkbf2(w0.x, w0.y);
      wfr[nt][kk].u[1] = pkbf2(w0.z, w0.w);
      wfr[nt][kk].u[2] = pkbf2(w1.x, w1.y);
      wfr[nt][kk].u[3] = pkbf2(w1.z, w1.w);
    }
  }

  // A-frag layout: lane supplies row=l15 (of 16-row chunk), k=(lane>>4)*8 + j
  const float* pA = A + (((size_t)(rowblk + l15)) << 8) + (lhi << 3);

  float4 fa[8], fb[8];   // half-buffers: fa = k 0..127, fb = k 128..255
  #pragma unroll
  for (int kk = 0; kk < 4; ++kk) {
    fa[2*kk]   = *(const float4*)(pA + kk * 32);
    fa[2*kk+1] = *(const float4*)(pA + kk * 32 + 4);
    fb[2*kk]   = *(const float4*)(pA + 128 + kk * 32);
    fb[2*kk+1] = *(const float4*)(pA + 128 + kk * 32 + 4);
  }

  for (int c = 0; c < 16; ++c) {
    v4f acc[4] = {};
    const float* pAn = pA + (size_t)(c + 1) * 4096;   // next chunk (c+1)*16 rows

    // first half: kk 0..3 from fa
    #pragma unroll
    for (int kk = 0; kk < 4; ++kk) {
      frag_u af;
      af.u[0] = pkbf2(fa[2*kk].x,   fa[2*kk].y);
      af.u[1] = pkbf2(fa[2*kk].z,   fa[2*kk].w);
      af.u[2] = pkbf2(fa[2*kk+1].x, fa[2*kk+1].y);
      af.u[3] = pkbf2(fa[2*kk+1].z, fa[2*kk+1].w);
      #pragma unroll
      for (int nt = 0; nt < 4; ++nt)
        acc[nt] = __builtin_amdgcn_mfma_f32_16x16x32_bf16(af.s, wfr[nt][kk].s, acc[nt], 0, 0, 0);
    }
    // refill fa for chunk c+1; latency hides under fb's cvt+MFMAs below
    if (c + 1 < 16) {
      #pragma unroll
      for (int kk = 0; kk < 4; ++kk) {
        fa[2*kk]   = *(const float4*)(pAn + kk * 32);
        fa[2*kk+1] = *(const float4*)(pAn + kk * 32 + 4);
      }
    }

    // second half: kk 4..7 from fb
    #pragma unroll
    for (int kk = 0; kk < 4; ++kk) {
      frag_u af;
      af.u[0] = pkbf2(fb[2*kk].x,   fb[2*kk].y);
      af.u[1] = pkbf2(fb[2*kk].z,   fb[2*kk].w);
      af.u[2] = pkbf2(fb[2*kk+1].x, fb[2*kk+1].y);
      af.u[3] = pkbf2(fb[2*kk+1].z, fb[2*kk+1].w);
      #pragma unroll
      for (int nt = 0; nt < 4; ++nt)
        acc[nt] = __builtin_amdgcn_mfma_f32_16x16x32_bf16(af.s, wfr[nt][kk + 4].s, acc[nt], 0, 0, 0);
    }
    if (c + 1 < 16) {
      #pragma unroll
      for (int kk = 0; kk < 4; ++kk) {
        fb[2*kk]   = *(const float4*)(pAn + 128 + kk * 32);
        fb[2*kk+1] = *(const float4*)(pAn + 128 + kk * 32 + 4);
      }
    }

    // epilogue: C/D layout col=lane&15, row=(lane>>4)*4+r
    const int mrow = rowblk + c * 16 + lhi * 4;
    #pragma unroll
    for (int nt = 0; nt < 4; ++nt) {
      const int col = c0 + nt * 16 + l15;
      #pragma unroll
      for (int r = 0; r < 4; ++r)
        C[(((size_t)(mrow + r)) << 8) + col] = f2bf(acc[nt][r]);
    }
  }
}

// ---------------- Phase 2: sequential scan, 1 thread per (b,h) channel ----------------
// h_t = relu(xw_t + w * h_{t-1}); out[t*BH + ch] = h_t; out[TBH + ch] = h_last
__global__ __launch_bounds__(64) void indrnn_scan(
    const ushort* __restrict__ xw,
    const float* __restrict__ h0,
    const float* __restrict__ w_hh,
    float* __restrict__ out)
{
  const int ch = blockIdx.x * 64 + threadIdx.x;   // 256 blocks x 64 = 16384 channels
  const float w = w_hh[ch & 255];
  float h = h0[ch];
  const ushort* px = xw + ch;
  float* po = out + ch;

  uint b0[BATCH], b1[BATCH], b2[BATCH], b3[BATCH];

  auto ld = [&](uint (&buf)[BATCH], int kb) {
    const ushort* p = px + (size_t)kb * BATCH * BH;
    #pragma unroll
    for (int j = 0; j < BATCH; ++j) buf[j] = p[(size_t)j * BH];
  };
  auto cp = [&](uint (&buf)[BATCH], int kb) {
    float* o = po + (size_t)kb * BATCH * BH;
    #pragma unroll
    for (int j = 0; j < BATCH; ++j) {
      float xv = __uint_as_float(buf[j] << 16);
      h = fmaxf(fmaf(h, w, xv), 0.0f);
      o[(size_t)j * BH] = h;
    }
  };

  ld(b0, 0); ld(b1, 1); ld(b2, 2); ld(b3, 3);
  for (int kb = 0; kb < NBATCH; kb += 4) {
    cp(b0, kb);     if (kb + 4 < NBATCH) ld(b0, kb + 4);
    cp(b1, kb + 1); if (kb + 5 < NBATCH) ld(b1, kb + 5);
    cp(b2, kb + 2); if (kb + 6 < NBATCH) ld(b2, kb + 6);
    cp(b3, kb + 3); if (kb + 7 < NBATCH) ld(b3, kb + 7);
  }
  out[(size_t)TBH + ch] = h;
}

extern "C" void kernel_launch(void* const* d_in, const int* in_sizes, int n_in,
                              void* d_out, int out_size, void* d_ws, size_t ws_size,
                              hipStream_t stream) {
  const float* x    = (const float*)d_in[0];   // [2048, 64, 256]
  const float* h0   = (const float*)d_in[1];   // [1, 64, 256]
  const float* W_ih = (const float*)d_in[2];   // [256, 256]
  const float* w_hh = (const float*)d_in[3];   // [256]
  float* out = (float*)d_out;                  // [T,B,H] ++ [1,B,H]
  ushort* xw = (ushort*)d_ws;                  // bf16 intermediate, 64 MB

  indrnn_gemm<<<dim3(512), dim3(256), 0, stream>>>(x, W_ih, xw);
  indrnn_scan<<<dim3(256), dim3(64), 0, stream>>>(xw, h0, w_hh, out);
}